// Round 13
// baseline (429.789 us; speedup 1.0000x reference)
//
#include <hip/hip_runtime.h>
#include <hip/hip_bf16.h>

// NodeModel: edge MLP ([x[col]||edge_attr] -> 64 relu -> 64 relu) -> scatter_mean
// over row -> node MLP ([x||agg||u[batch]] -> 64 relu -> 32).
// N=50000, E=1.6M, D_H=64.
//
// R13: R11 register-resident edge kernel (153us, VGPR 76, k=3 — the proven
// no-spill point; R12's k=4 spilled again: VGPR pinned 64, FETCH 413MB) +
// TWO 16-edge sub-tiles per iteration: both metas+gathers issue together
// (64 random lines in flight vs 32) and chain B's latency hides under chain
// A's MFMA/VALU. Unlike R10's failed pairing (R5 structure: 3 LDS round
// trips per chain), R11's chains only touch the tiny H2 bounce.
// sorted int4 -> int2 {eid, col|row<<16}: halves permute scatter payload
// and meta reads. 32-edge flush merges boundary runs.

typedef __attribute__((ext_vector_type(8))) short bf16x8;
typedef __attribute__((ext_vector_type(4))) float f32x4;

__device__ __forceinline__ unsigned short f2bf(float f) {
    union { float f; unsigned u; } v; v.f = f;
    return (unsigned short)((v.u + 0x7FFFu + ((v.u >> 16) & 1u)) >> 16);
}

// ---------------- counting sort ----------------

__global__ __launch_bounds__(256) void count_rows(
    const int* __restrict__ erow, int* __restrict__ counts, int E)
{
    const int gid = blockIdx.x * blockDim.x + threadIdx.x;
    const int stride = gridDim.x * blockDim.x;
    const int n4 = E >> 2;
    for (int i = gid; i < n4; i += stride) {
        const int4 r = ((const int4*)erow)[i];
        atomicAdd(&counts[r.x], 1);
        atomicAdd(&counts[r.y], 1);
        atomicAdd(&counts[r.z], 1);
        atomicAdd(&counts[r.w], 1);
    }
    for (int i = (n4 << 2) + gid; i < E; i += stride)
        atomicAdd(&counts[erow[i]], 1);
}

__global__ __launch_bounds__(256) void scan_blocks(
    const int* __restrict__ counts, int* __restrict__ excl,
    int* __restrict__ bsum, int N)
{
    __shared__ int tmp[256];
    const int t = threadIdx.x;
    const int i = blockIdx.x * 256 + t;
    const int v = (i < N) ? counts[i] : 0;
    tmp[t] = v; __syncthreads();
#pragma unroll
    for (int o = 1; o < 256; o <<= 1) {
        const int a = (t >= o) ? tmp[t - o] : 0;
        __syncthreads();
        tmp[t] += a;
        __syncthreads();
    }
    if (i < N) excl[i] = tmp[t] - v;
    if (t == 255) bsum[blockIdx.x] = tmp[t];
}

__global__ __launch_bounds__(256) void scan_bsum(int* __restrict__ bsum, int nb)
{
    __shared__ int tmp[256];
    const int t = threadIdx.x;
    const int v = (t < nb) ? bsum[t] : 0;
    tmp[t] = v; __syncthreads();
#pragma unroll
    for (int o = 1; o < 256; o <<= 1) {
        const int a = (t >= o) ? tmp[t - o] : 0;
        __syncthreads();
        tmp[t] += a;
        __syncthreads();
    }
    if (t < nb) bsum[t] = tmp[t] - v;   // exclusive
}

__global__ __launch_bounds__(256) void scan_add(
    int* __restrict__ rowstart, int* __restrict__ cursor,
    const int* __restrict__ bsum, int N, int E)
{
    const int i = blockIdx.x * 256 + threadIdx.x;
    if (i < N) {
        const int v = rowstart[i] + bsum[blockIdx.x];
        rowstart[i] = v;
        cursor[i]   = v;
    }
    if (i == 0) rowstart[N] = E;
}

// sorted2[pos] = {eid, col | row<<16}
__global__ __launch_bounds__(256) void permute_edges(
    const int* __restrict__ erow, const int* __restrict__ ecol,
    int* __restrict__ cursor, int2* __restrict__ sorted2, int E)
{
    const int gid = blockIdx.x * blockDim.x + threadIdx.x;
    const int stride = gridDim.x * blockDim.x;
    const int n4 = E >> 2;
    for (int i = gid; i < n4; i += stride) {
        const int4 r = ((const int4*)erow)[i];
        const int4 c = ((const int4*)ecol)[i];
        const int e0 = i << 2;
        int pos;
        pos = atomicAdd(&cursor[r.x], 1);
        sorted2[pos] = int2{e0,     (int)((unsigned)c.x | ((unsigned)r.x << 16))};
        pos = atomicAdd(&cursor[r.y], 1);
        sorted2[pos] = int2{e0 + 1, (int)((unsigned)c.y | ((unsigned)r.y << 16))};
        pos = atomicAdd(&cursor[r.z], 1);
        sorted2[pos] = int2{e0 + 2, (int)((unsigned)c.z | ((unsigned)r.z << 16))};
        pos = atomicAdd(&cursor[r.w], 1);
        sorted2[pos] = int2{e0 + 3, (int)((unsigned)c.w | ((unsigned)r.w << 16))};
    }
    for (int i = (n4 << 2) + gid; i < E; i += stride) {
        const int r = erow[i];
        const int pos = atomicAdd(&cursor[r], 1);
        sorted2[pos] = int2{i, (int)((unsigned)ecol[i] | ((unsigned)r << 16))};
    }
}

// ---------------- edge MLP (sorted, register-resident, paired sub-tiles) ----------------

__global__ __launch_bounds__(256, 3) void edge_mlp_mfma(
    const float* __restrict__ x,        // [N,32]
    const int2*  __restrict__ sorted2,  // [E] {eid, col|row<<16}
    const float* __restrict__ eattr,    // [E,32]
    const float* __restrict__ W1a,      // [64,64] (in,out)
    const float* __restrict__ b1a,      // [64]
    const float* __restrict__ W1b,      // [64,64]
    const float* __restrict__ b1b,      // [64]
    float* __restrict__ summed,         // [N,64]
    int E)
{
    // H2 bounce: wave-private, 2 sub-tiles x [16 edges][64 hid] bf16 (4KB/wave).
    __shared__ __align__(16) unsigned short H2[4 * 2 * 16 * 64];  // 16KB

    const int tid  = threadIdx.x;
    const int lane = tid & 63;
    const int wv   = tid >> 6;
    const int g    = lane >> 4;
    const int el   = lane & 15;

    unsigned short* const h2A = H2 + wv * (2 * 16 * 64);
    unsigned short* const h2B = h2A + 16 * 64;

    // persistent weight fragments: A row = lane&15, k = 8*(lane>>4)+j;
    // B col = lane&15, same k (identical mappings)
    bf16x8 wa[4][2], wb[4][2];
    f32x4  bias1[4];
    float  bias2s[4];
#pragma unroll
    for (int mt = 0; mt < 4; ++mt) {
        const int o = mt * 16 + el;
#pragma unroll
        for (int ks = 0; ks < 2; ++ks) {
            bf16x8 ta, tb;
#pragma unroll
            for (int j = 0; j < 8; ++j) {
                const int k = ks * 32 + 8 * g + j;
                ta[j] = (short)f2bf(W1a[k * 64 + o]);
                tb[j] = (short)f2bf(W1b[k * 64 + o]);
            }
            wa[mt][ks] = ta;
            wb[mt][ks] = tb;
        }
#pragma unroll
        for (int r = 0; r < 4; ++r) bias1[mt][r] = b1a[mt * 16 + 4 * g + r];
        bias2s[mt] = b1b[o];
    }

    const int ntile = (E + 31) >> 5;              // 32-edge tiles
    const int wid   = blockIdx.x * 4 + wv;
    const int nw    = gridDim.x * 4;

    const int sw = el & 7;   // H2 swizzle

    for (int t = wid; t < ntile; t += nw) {
        const int ebase = t << 5;

        // ---- meta for BOTH sub-tiles (lane (g,el) -> edge el / 16+el) ----
        int2 sA, sB; int rowA, rowB;
        if (ebase + el < E) {
            sA = sorted2[ebase + el];
            rowA = (int)((unsigned)sA.y >> 16);
        } else { sA = int2{0, 0}; rowA = -1; }
        if (ebase + 16 + el < E) {
            sB = sorted2[ebase + 16 + el];
            rowB = (int)((unsigned)sB.y >> 16);
        } else { sB = int2{0, 0}; rowB = -1; }

        // ---- BOTH gathers issue together: 4x32B per lane in flight ----
        float4 ax0, ax1, aa0, aa1, bx0, bx1, ba0, ba1;
        {
            const float4* xpA = (const float4*)(x + (size_t)(sA.y & 0xFFFF) * 32 + 8 * g);
            const float4* apA = (const float4*)(eattr + (size_t)sA.x * 32 + 8 * g);
            const float4* xpB = (const float4*)(x + (size_t)(sB.y & 0xFFFF) * 32 + 8 * g);
            const float4* apB = (const float4*)(eattr + (size_t)sB.x * 32 + 8 * g);
            ax0 = xpA[0]; ax1 = xpA[1];
            aa0 = apA[0]; aa1 = apA[1];
            bx0 = xpB[0]; bx1 = xpB[1];
            ba0 = apB[0]; ba1 = apB[1];
        }

        // ================= chain A =================
        bf16x8 bf0, bf1;
        bf0[0] = (short)f2bf(ax0.x); bf0[1] = (short)f2bf(ax0.y);
        bf0[2] = (short)f2bf(ax0.z); bf0[3] = (short)f2bf(ax0.w);
        bf0[4] = (short)f2bf(ax1.x); bf0[5] = (short)f2bf(ax1.y);
        bf0[6] = (short)f2bf(ax1.z); bf0[7] = (short)f2bf(ax1.w);
        bf1[0] = (short)f2bf(aa0.x); bf1[1] = (short)f2bf(aa0.y);
        bf1[2] = (short)f2bf(aa0.z); bf1[3] = (short)f2bf(aa0.w);
        bf1[4] = (short)f2bf(aa1.x); bf1[5] = (short)f2bf(aa1.y);
        bf1[6] = (short)f2bf(aa1.z); bf1[7] = (short)f2bf(aa1.w);

        f32x4 a0 = bias1[0], a1 = bias1[1], a2 = bias1[2], a3 = bias1[3];
        a0 = __builtin_amdgcn_mfma_f32_16x16x32_bf16(wa[0][0], bf0, a0, 0, 0, 0);
        a1 = __builtin_amdgcn_mfma_f32_16x16x32_bf16(wa[1][0], bf0, a1, 0, 0, 0);
        a2 = __builtin_amdgcn_mfma_f32_16x16x32_bf16(wa[2][0], bf0, a2, 0, 0, 0);
        a3 = __builtin_amdgcn_mfma_f32_16x16x32_bf16(wa[3][0], bf0, a3, 0, 0, 0);
        a0 = __builtin_amdgcn_mfma_f32_16x16x32_bf16(wa[0][1], bf1, a0, 0, 0, 0);
        a1 = __builtin_amdgcn_mfma_f32_16x16x32_bf16(wa[1][1], bf1, a1, 0, 0, 0);
        a2 = __builtin_amdgcn_mfma_f32_16x16x32_bf16(wa[2][1], bf1, a2, 0, 0, 0);
        a3 = __builtin_amdgcn_mfma_f32_16x16x32_bf16(wa[3][1], bf1, a3, 0, 0, 0);

        unsigned short* hrowA = h2A + el * 64;
        {
            f32x4 accs[4] = {a0, a1, a2, a3};
#pragma unroll
            for (int mt = 0; mt < 4; ++mt) {
                unsigned short pk[4];
#pragma unroll
                for (int r = 0; r < 4; ++r) pk[r] = f2bf(fmaxf(accs[mt][r], 0.f));
                const int hid   = mt * 16 + 4 * g;
                const int chunk = hid >> 3;
                const int off   = hid & 7;
                *(uint2*)(hrowA + ((chunk ^ sw) * 8 + off)) = *(uint2*)pk;
            }
        }
        const bf16x8 ha0 = *(const bf16x8*)(hrowA + (((0 + g) ^ sw) * 8));
        const bf16x8 ha1 = *(const bf16x8*)(hrowA + (((4 + g) ^ sw) * 8));
        f32x4 dA0 = {bias2s[0], bias2s[0], bias2s[0], bias2s[0]};
        f32x4 dA1 = {bias2s[1], bias2s[1], bias2s[1], bias2s[1]};
        f32x4 dA2 = {bias2s[2], bias2s[2], bias2s[2], bias2s[2]};
        f32x4 dA3 = {bias2s[3], bias2s[3], bias2s[3], bias2s[3]};
        dA0 = __builtin_amdgcn_mfma_f32_16x16x32_bf16(ha0, wb[0][0], dA0, 0, 0, 0);
        dA1 = __builtin_amdgcn_mfma_f32_16x16x32_bf16(ha0, wb[1][0], dA1, 0, 0, 0);
        dA2 = __builtin_amdgcn_mfma_f32_16x16x32_bf16(ha0, wb[2][0], dA2, 0, 0, 0);
        dA3 = __builtin_amdgcn_mfma_f32_16x16x32_bf16(ha0, wb[3][0], dA3, 0, 0, 0);
        dA0 = __builtin_amdgcn_mfma_f32_16x16x32_bf16(ha1, wb[0][1], dA0, 0, 0, 0);
        dA1 = __builtin_amdgcn_mfma_f32_16x16x32_bf16(ha1, wb[1][1], dA1, 0, 0, 0);
        dA2 = __builtin_amdgcn_mfma_f32_16x16x32_bf16(ha1, wb[2][1], dA2, 0, 0, 0);
        dA3 = __builtin_amdgcn_mfma_f32_16x16x32_bf16(ha1, wb[3][1], dA3, 0, 0, 0);

        // ================= chain B =================
        bf16x8 cf0, cf1;
        cf0[0] = (short)f2bf(bx0.x); cf0[1] = (short)f2bf(bx0.y);
        cf0[2] = (short)f2bf(bx0.z); cf0[3] = (short)f2bf(bx0.w);
        cf0[4] = (short)f2bf(bx1.x); cf0[5] = (short)f2bf(bx1.y);
        cf0[6] = (short)f2bf(bx1.z); cf0[7] = (short)f2bf(bx1.w);
        cf1[0] = (short)f2bf(ba0.x); cf1[1] = (short)f2bf(ba0.y);
        cf1[2] = (short)f2bf(ba0.z); cf1[3] = (short)f2bf(ba0.w);
        cf1[4] = (short)f2bf(ba1.x); cf1[5] = (short)f2bf(ba1.y);
        cf1[6] = (short)f2bf(ba1.z); cf1[7] = (short)f2bf(ba1.w);

        f32x4 b0 = bias1[0], b1 = bias1[1], b2 = bias1[2], b3 = bias1[3];
        b0 = __builtin_amdgcn_mfma_f32_16x16x32_bf16(wa[0][0], cf0, b0, 0, 0, 0);
        b1 = __builtin_amdgcn_mfma_f32_16x16x32_bf16(wa[1][0], cf0, b1, 0, 0, 0);
        b2 = __builtin_amdgcn_mfma_f32_16x16x32_bf16(wa[2][0], cf0, b2, 0, 0, 0);
        b3 = __builtin_amdgcn_mfma_f32_16x16x32_bf16(wa[3][0], cf0, b3, 0, 0, 0);
        b0 = __builtin_amdgcn_mfma_f32_16x16x32_bf16(wa[0][1], cf1, b0, 0, 0, 0);
        b1 = __builtin_amdgcn_mfma_f32_16x16x32_bf16(wa[1][1], cf1, b1, 0, 0, 0);
        b2 = __builtin_amdgcn_mfma_f32_16x16x32_bf16(wa[2][1], cf1, b2, 0, 0, 0);
        b3 = __builtin_amdgcn_mfma_f32_16x16x32_bf16(wa[3][1], cf1, b3, 0, 0, 0);

        unsigned short* hrowB = h2B + el * 64;
        {
            f32x4 accs[4] = {b0, b1, b2, b3};
#pragma unroll
            for (int mt = 0; mt < 4; ++mt) {
                unsigned short pk[4];
#pragma unroll
                for (int r = 0; r < 4; ++r) pk[r] = f2bf(fmaxf(accs[mt][r], 0.f));
                const int hid   = mt * 16 + 4 * g;
                const int chunk = hid >> 3;
                const int off   = hid & 7;
                *(uint2*)(hrowB + ((chunk ^ sw) * 8 + off)) = *(uint2*)pk;
            }
        }
        const bf16x8 hb0 = *(const bf16x8*)(hrowB + (((0 + g) ^ sw) * 8));
        const bf16x8 hb1 = *(const bf16x8*)(hrowB + (((4 + g) ^ sw) * 8));
        f32x4 dB0 = {bias2s[0], bias2s[0], bias2s[0], bias2s[0]};
        f32x4 dB1 = {bias2s[1], bias2s[1], bias2s[1], bias2s[1]};
        f32x4 dB2 = {bias2s[2], bias2s[2], bias2s[2], bias2s[2]};
        f32x4 dB3 = {bias2s[3], bias2s[3], bias2s[3], bias2s[3]};
        dB0 = __builtin_amdgcn_mfma_f32_16x16x32_bf16(hb0, wb[0][0], dB0, 0, 0, 0);
        dB1 = __builtin_amdgcn_mfma_f32_16x16x32_bf16(hb0, wb[1][0], dB1, 0, 0, 0);
        dB2 = __builtin_amdgcn_mfma_f32_16x16x32_bf16(hb0, wb[2][0], dB2, 0, 0, 0);
        dB3 = __builtin_amdgcn_mfma_f32_16x16x32_bf16(hb0, wb[3][0], dB3, 0, 0, 0);
        dB0 = __builtin_amdgcn_mfma_f32_16x16x32_bf16(hb1, wb[0][1], dB0, 0, 0, 0);
        dB1 = __builtin_amdgcn_mfma_f32_16x16x32_bf16(hb1, wb[1][1], dB1, 0, 0, 0);
        dB2 = __builtin_amdgcn_mfma_f32_16x16x32_bf16(hb1, wb[2][1], dB2, 0, 0, 0);
        dB3 = __builtin_amdgcn_mfma_f32_16x16x32_bf16(hb1, wb[3][1], dB3, 0, 0, 0);

        // ---- relu both (in registers) ----
#pragma unroll
        for (int r = 0; r < 4; ++r) {
            dA0[r] = fmaxf(dA0[r], 0.f); dA1[r] = fmaxf(dA1[r], 0.f);
            dA2[r] = fmaxf(dA2[r], 0.f); dA3[r] = fmaxf(dA3[r], 0.f);
            dB0[r] = fmaxf(dB0[r], 0.f); dB1[r] = fmaxf(dB1[r], 0.f);
            dB2[r] = fmaxf(dB2[r], 0.f); dB3[r] = fmaxf(dB3[r], 0.f);
        }

        // ---- register-space segmented flush over 32 sorted edges ----
        const int prevA = __shfl(rowA, lane - 1);
        unsigned long long mA = __ballot((g == 0) && (el > 0) && (rowA != prevA));
        const int prevB = __shfl(rowB, lane - 1);
        unsigned long long mB = __ballot((g == 0) && (el > 0) && (rowB != prevB));
        const int lastA  = __shfl(rowA, 15);
        const int firstB = __shfl(rowB, 0);
        unsigned long long bmask = (mA & 0xFFFEull)
                                 | ((mB & 0xFFFEull) << 16)
                                 | ((unsigned long long)(firstB != lastA) << 16)
                                 | (1ull << 32);

        int s = 0;
        while (s < 32) {
            const int e = s + 1 + (__ffsll(bmask >> (s + 1)) - 1);
            const int rowid = (s < 16) ? __shfl(rowA, s) : __shfl(rowB, s - 16);
            if (rowid >= 0) {
                float s0 = 0.f, s1 = 0.f, s2 = 0.f, s3 = 0.f;
#pragma unroll
                for (int r = 0; r < 4; ++r) {
                    const int ejA = 4 * g + r;
                    const int ejB = 16 + ejA;
                    const bool inA = (ejA >= s) && (ejA < e);
                    const bool inB = (ejB >= s) && (ejB < e);
                    s0 += (inA ? dA0[r] : 0.f) + (inB ? dB0[r] : 0.f);
                    s1 += (inA ? dA1[r] : 0.f) + (inB ? dB1[r] : 0.f);
                    s2 += (inA ? dA2[r] : 0.f) + (inB ? dB2[r] : 0.f);
                    s3 += (inA ? dA3[r] : 0.f) + (inB ? dB3[r] : 0.f);
                }
                s0 += __shfl_xor(s0, 16); s0 += __shfl_xor(s0, 32);
                s1 += __shfl_xor(s1, 16); s1 += __shfl_xor(s1, 32);
                s2 += __shfl_xor(s2, 16); s2 += __shfl_xor(s2, 32);
                s3 += __shfl_xor(s3, 16); s3 += __shfl_xor(s3, 32);
                const float val = (g == 0) ? s0 : (g == 1) ? s1
                                : (g == 2) ? s2 : s3;
                unsafeAtomicAdd(&summed[(size_t)rowid * 64 + lane], val);
            }
            s = e;
        }
    }
}

// ---------------- node MLP via MFMA ----------------

__global__ __launch_bounds__(256, 2) void node_mlp_mfma(
    const float* __restrict__ x,        // [N,32]
    const float* __restrict__ summed,   // [N,64]
    const int*   __restrict__ rowstart, // [N+1]
    const float* __restrict__ u,        // [G,16]
    const int*   __restrict__ batch,    // [N]
    const float* __restrict__ W2a,      // [112,64]
    const float* __restrict__ b2a,      // [64]
    const float* __restrict__ W2b,      // [64,32]
    const float* __restrict__ b2b,      // [32]
    float* __restrict__ out,            // [N,32]
    int N)
{
    __shared__ __align__(16) unsigned short In[64 * 128];  // 16KB
    __shared__ __align__(16) unsigned short H[64 * 64];    // 8KB

    const int tid  = threadIdx.x;
    const int lane = tid & 63;
    const int wv   = tid >> 6;
    const int g    = lane >> 4;
    const int el   = lane & 15;

    bf16x8 wa[4][4];
    f32x4  bias1[4];
#pragma unroll
    for (int mt = 0; mt < 4; ++mt) {
        const int o = mt * 16 + el;
#pragma unroll
        for (int ks = 0; ks < 4; ++ks) {
            bf16x8 ta;
#pragma unroll
            for (int j = 0; j < 8; ++j) {
                const int k = ks * 32 + 8 * g + j;
                ta[j] = (k < 112) ? (short)f2bf(W2a[k * 64 + o]) : (short)0;
            }
            wa[mt][ks] = ta;
        }
#pragma unroll
        for (int r = 0; r < 4; ++r) bias1[mt][r] = b2a[mt * 16 + 4 * g + r];
    }
    bf16x8 wb[2][2];
    float  bias2s[2];
#pragma unroll
    for (int nt = 0; nt < 2; ++nt) {
        const int o = nt * 16 + el;
#pragma unroll
        for (int ks = 0; ks < 2; ++ks) {
            bf16x8 tb;
#pragma unroll
            for (int j = 0; j < 8; ++j) {
                const int k = ks * 32 + 8 * g + j;
                tb[j] = (short)f2bf(W2b[k * 32 + o]);
            }
            wb[nt][ks] = tb;
        }
        bias2s[nt] = b2b[o];
    }

    unsigned short* const inrow = In + (wv * 16) * 128;
    unsigned short* const hrow0 = H + (wv * 16) * 64;

    const int ntile = (N + 15) >> 4;
    const int wid   = blockIdx.x * 4 + wv;
    const int nw    = gridDim.x * 4;

    for (int t = wid; t < ntile; t += nw) {
        const int nbase = t << 4;

        // ---- stage 16 nodes: 4 lanes/node, 32-float segment each ----
        // row layout (128 bf16): [x(32) | agg(32) | agg(32) | u(16)+0(16)]
        {
            const int le = lane >> 2;
            const int p  = lane & 3;
            const int n  = nbase + le;
            float4 v[8];
            if (n < N) {
                if (p == 0) {
                    const float4* xp = (const float4*)(x + (size_t)n * 32);
#pragma unroll
                    for (int q = 0; q < 8; ++q) v[q] = xp[q];
                } else if (p < 3) {
                    const int cnt = rowstart[n + 1] - rowstart[n];
                    const float inv = 1.0f / fmaxf((float)cnt, 1.0f);
                    const float4* sp = (const float4*)(summed + (size_t)n * 64 + (p - 1) * 32);
#pragma unroll
                    for (int q = 0; q < 8; ++q) {
                        v[q] = sp[q];
                        v[q].x *= inv; v[q].y *= inv; v[q].z *= inv; v[q].w *= inv;
                    }
                } else {
                    const int gb = batch[n];
                    const float4* up = (const float4*)(u + (size_t)gb * 16);
#pragma unroll
                    for (int q = 0; q < 4; ++q) v[q] = up[q];
#pragma unroll
                    for (int q = 4; q < 8; ++q) v[q] = float4{0.f, 0.f, 0.f, 0.f};
                }
            } else {
#pragma unroll
                for (int q = 0; q < 8; ++q) v[q] = float4{0.f, 0.f, 0.f, 0.f};
            }
            const int sw = le & 7;
            unsigned short* row = inrow + le * 128;
#pragma unroll
            for (int q = 0; q < 4; ++q) {
                bf16x8 c;
                const float4 va = v[2 * q], vb = v[2 * q + 1];
                c[0] = (short)f2bf(va.x); c[1] = (short)f2bf(va.y);
                c[2] = (short)f2bf(va.z); c[3] = (short)f2bf(va.w);
                c[4] = (short)f2bf(vb.x); c[5] = (short)f2bf(vb.y);
                c[6] = (short)f2bf(vb.z); c[7] = (short)f2bf(vb.w);
                const int cc = 4 * p + q;
                const int ci = (cc & 8) | ((cc & 7) ^ sw);
                *(bf16x8*)(row + ci * 8) = c;
            }
        }

        // ---- layer 1: 16 MFMAs over K=128 ----
        const unsigned short* brow = inrow + el * 128;
        const int sw7 = el & 7;
        f32x4 a0 = bias1[0], a1 = bias1[1], a2 = bias1[2], a3 = bias1[3];
#pragma unroll
        for (int ks = 0; ks < 4; ++ks) {
            const int cc = ks * 4 + g;
            const int ci = (cc & 8) | ((cc & 7) ^ sw7);
            const bf16x8 bf = *(const bf16x8*)(brow + ci * 8);
            a0 = __builtin_amdgcn_mfma_f32_16x16x32_bf16(wa[0][ks], bf, a0, 0, 0, 0);
            a1 = __builtin_amdgcn_mfma_f32_16x16x32_bf16(wa[1][ks], bf, a1, 0, 0, 0);
            a2 = __builtin_amdgcn_mfma_f32_16x16x32_bf16(wa[2][ks], bf, a2, 0, 0, 0);
            a3 = __builtin_amdgcn_mfma_f32_16x16x32_bf16(wa[3][ks], bf, a3, 0, 0, 0);
        }

        // ---- relu -> bf16 -> H (swizzled by el&7) ----
        unsigned short* hrow = hrow0 + el * 64;
        {
            f32x4 accs[4] = {a0, a1, a2, a3};
#pragma unroll
            for (int mt = 0; mt < 4; ++mt) {
                unsigned short pk[4];
#pragma unroll
                for (int r = 0; r < 4; ++r) pk[r] = f2bf(fmaxf(accs[mt][r], 0.f));
                const int hid   = mt * 16 + 4 * g;
                const int chunk = hid >> 3;
                const int off   = hid & 7;
                *(uint2*)(hrow + ((chunk ^ sw7) * 8 + off)) = *(uint2*)pk;
            }
        }

        // ---- layer 2 operand-swapped: D = H (A) x W2b (B) -> node-major ----
        const bf16x8 hb0 = *(const bf16x8*)(hrow + (((0 + g) ^ sw7) * 8));
        const bf16x8 hb1 = *(const bf16x8*)(hrow + (((4 + g) ^ sw7) * 8));
        f32x4 dn0 = {bias2s[0], bias2s[0], bias2s[0], bias2s[0]};
        f32x4 dn1 = {bias2s[1], bias2s[1], bias2s[1], bias2s[1]};
        dn0 = __builtin_amdgcn_mfma_f32_16x16x32_bf16(hb0, wb[0][0], dn0, 0, 0, 0);
        dn1 = __builtin_amdgcn_mfma_f32_16x16x32_bf16(hb0, wb[1][0], dn1, 0, 0, 0);
        dn0 = __builtin_amdgcn_mfma_f32_16x16x32_bf16(hb1, wb[0][1], dn0, 0, 0, 0);
        dn1 = __builtin_amdgcn_mfma_f32_16x16x32_bf16(hb1, wb[1][1], dn1, 0, 0, 0);

        // ---- store: lane holds node 4g+r, out nt*16+el ----
        if (nbase + 16 <= N) {
#pragma unroll
            for (int r = 0; r < 4; ++r) {
                float* dst = out + (size_t)(nbase + 4 * g + r) * 32 + el;
                dst[0]  = dn0[r];
                dst[16] = dn1[r];
            }
        } else {
#pragma unroll
            for (int r = 0; r < 4; ++r) {
                const int n = nbase + 4 * g + r;
                if (n < N) {
                    float* dst = out + (size_t)n * 32 + el;
                    dst[0]  = dn0[r];
                    dst[16] = dn1[r];
                }
            }
        }
    }
}

extern "C" void kernel_launch(void* const* d_in, const int* in_sizes, int n_in,
                              void* d_out, int out_size, void* d_ws, size_t ws_size,
                              hipStream_t stream) {
    const float* x     = (const float*)d_in[0];
    const int*   eidx  = (const int*)d_in[1];   // [2,E] int32
    const float* eattr = (const float*)d_in[2];
    const float* u     = (const float*)d_in[3];
    const int*   batch = (const int*)d_in[4];
    const float* W1a   = (const float*)d_in[5];
    const float* b1a   = (const float*)d_in[6];
    const float* W1b   = (const float*)d_in[7];
    const float* b1b   = (const float*)d_in[8];
    const float* W2a   = (const float*)d_in[9];
    const float* b2a   = (const float*)d_in[10];
    const float* W2b   = (const float*)d_in[11];
    const float* b2b   = (const float*)d_in[12];
    float* out = (float*)d_out;

    const int N = in_sizes[0] / 32;
    const int E = in_sizes[1] / 2;
    const int* erow = eidx;
    const int* ecol = eidx + E;

    // ws: sorted2[E] | summed[N*64] f32 | counts[N] | rowstart[N+1] | cursor[N] | bsum[256]
    int2*  sorted2  = (int2*)d_ws;
    float* summed   = (float*)(sorted2 + E);
    int*   counts   = (int*)(summed + (size_t)N * 64);
    int*   rowstart = counts + N;
    int*   cursor   = rowstart + (N + 1);
    int*   bsum     = cursor + N;

    // zero summed + counts (contiguous)
    hipMemsetAsync(summed, 0, ((size_t)N * 64 + N) * sizeof(float), stream);

    count_rows<<<1024, 256, 0, stream>>>(erow, counts, E);
    const int nb = (N + 255) / 256;
    scan_blocks<<<nb, 256, 0, stream>>>(counts, rowstart, bsum, N);
    scan_bsum<<<1, 256, 0, stream>>>(bsum, nb);
    scan_add<<<nb, 256, 0, stream>>>(rowstart, cursor, bsum, N, E);
    permute_edges<<<1024, 256, 0, stream>>>(erow, ecol, cursor, sorted2, E);

    edge_mlp_mfma<<<4096, 256, 0, stream>>>(x, sorted2, eattr,
                                            W1a, b1a, W1b, b1b, summed, E);
    node_mlp_mfma<<<784, 256, 0, stream>>>(x, summed, rowstart, u, batch,
                                           W2a, b2a, W2b, b2b, out, N);
}

// Round 14
// 314.698 us; speedup vs baseline: 1.3657x; 1.3657x over previous
//
#include <hip/hip_runtime.h>
#include <hip/hip_bf16.h>

// NodeModel: edge MLP ([x[col]||edge_attr] -> 64 relu -> 64 relu) -> scatter_mean
// over row -> node MLP ([x||agg||u[batch]] -> 64 relu -> 32).
// N=50000, E=1.6M, D_H=64.
//
// R14: REVERT to R11's edge structure (153us; 76 VGPR, k=3 — the unique
// no-spill point; R13's paired chains hit the 512/(2k)=85 cap and spilled:
// FETCH 450MB). Changes vs R11, all within the register envelope:
//  - f2bf: software round-to-nearest (5 VALU inst) -> HW (__bf16) cast;
//    compiler emits v_cvt_pk_bf16_f32. ~32 converts/lane/tile was ~320cy
//    of the tile's VALU (VALUBusy 36%). Applies to edge+node kernels.
//  - sorted meta int4 -> int2 {eid, col|row<<16} (R13-proven): halves
//    permute scatter payload and edge meta bytes.
//  - scan_add also writes cursor (memcpy launch dropped, R12-proven).

typedef __attribute__((ext_vector_type(8))) short bf16x8;
typedef __attribute__((ext_vector_type(4))) float f32x4;

__device__ __forceinline__ unsigned short f2bf(float f) {
    __bf16 h = (__bf16)f;               // HW v_cvt_pk_bf16_f32 (RNE)
    unsigned short u;
    __builtin_memcpy(&u, &h, 2);
    return u;
}

// ---------------- counting sort ----------------

__global__ __launch_bounds__(256) void count_rows(
    const int* __restrict__ erow, int* __restrict__ counts, int E)
{
    const int gid = blockIdx.x * blockDim.x + threadIdx.x;
    const int stride = gridDim.x * blockDim.x;
    const int n4 = E >> 2;
    for (int i = gid; i < n4; i += stride) {
        const int4 r = ((const int4*)erow)[i];
        atomicAdd(&counts[r.x], 1);
        atomicAdd(&counts[r.y], 1);
        atomicAdd(&counts[r.z], 1);
        atomicAdd(&counts[r.w], 1);
    }
    for (int i = (n4 << 2) + gid; i < E; i += stride)
        atomicAdd(&counts[erow[i]], 1);
}

__global__ __launch_bounds__(256) void scan_blocks(
    const int* __restrict__ counts, int* __restrict__ excl,
    int* __restrict__ bsum, int N)
{
    __shared__ int tmp[256];
    const int t = threadIdx.x;
    const int i = blockIdx.x * 256 + t;
    const int v = (i < N) ? counts[i] : 0;
    tmp[t] = v; __syncthreads();
#pragma unroll
    for (int o = 1; o < 256; o <<= 1) {
        const int a = (t >= o) ? tmp[t - o] : 0;
        __syncthreads();
        tmp[t] += a;
        __syncthreads();
    }
    if (i < N) excl[i] = tmp[t] - v;
    if (t == 255) bsum[blockIdx.x] = tmp[t];
}

__global__ __launch_bounds__(256) void scan_bsum(int* __restrict__ bsum, int nb)
{
    __shared__ int tmp[256];
    const int t = threadIdx.x;
    const int v = (t < nb) ? bsum[t] : 0;
    tmp[t] = v; __syncthreads();
#pragma unroll
    for (int o = 1; o < 256; o <<= 1) {
        const int a = (t >= o) ? tmp[t - o] : 0;
        __syncthreads();
        tmp[t] += a;
        __syncthreads();
    }
    if (t < nb) bsum[t] = tmp[t] - v;   // exclusive
}

__global__ __launch_bounds__(256) void scan_add(
    int* __restrict__ rowstart, int* __restrict__ cursor,
    const int* __restrict__ bsum, int N, int E)
{
    const int i = blockIdx.x * 256 + threadIdx.x;
    if (i < N) {
        const int v = rowstart[i] + bsum[blockIdx.x];
        rowstart[i] = v;
        cursor[i]   = v;
    }
    if (i == 0) rowstart[N] = E;
}

// sorted2[pos] = {eid, col | row<<16}
__global__ __launch_bounds__(256) void permute_edges(
    const int* __restrict__ erow, const int* __restrict__ ecol,
    int* __restrict__ cursor, int2* __restrict__ sorted2, int E)
{
    const int gid = blockIdx.x * blockDim.x + threadIdx.x;
    const int stride = gridDim.x * blockDim.x;
    const int n4 = E >> 2;
    for (int i = gid; i < n4; i += stride) {
        const int4 r = ((const int4*)erow)[i];
        const int4 c = ((const int4*)ecol)[i];
        const int e0 = i << 2;
        int pos;
        pos = atomicAdd(&cursor[r.x], 1);
        sorted2[pos] = int2{e0,     (int)((unsigned)c.x | ((unsigned)r.x << 16))};
        pos = atomicAdd(&cursor[r.y], 1);
        sorted2[pos] = int2{e0 + 1, (int)((unsigned)c.y | ((unsigned)r.y << 16))};
        pos = atomicAdd(&cursor[r.z], 1);
        sorted2[pos] = int2{e0 + 2, (int)((unsigned)c.z | ((unsigned)r.z << 16))};
        pos = atomicAdd(&cursor[r.w], 1);
        sorted2[pos] = int2{e0 + 3, (int)((unsigned)c.w | ((unsigned)r.w << 16))};
    }
    for (int i = (n4 << 2) + gid; i < E; i += stride) {
        const int r = erow[i];
        const int pos = atomicAdd(&cursor[r], 1);
        sorted2[pos] = int2{i, (int)((unsigned)ecol[i] | ((unsigned)r << 16))};
    }
}

// ---------------- edge MLP (sorted, register-resident) ----------------

__global__ __launch_bounds__(256, 3) void edge_mlp_mfma(
    const float* __restrict__ x,        // [N,32]
    const int2*  __restrict__ sorted2,  // [E] {eid, col|row<<16}
    const float* __restrict__ eattr,    // [E,32]
    const float* __restrict__ W1a,      // [64,64] (in,out)
    const float* __restrict__ b1a,      // [64]
    const float* __restrict__ W1b,      // [64,64]
    const float* __restrict__ b1b,      // [64]
    float* __restrict__ summed,         // [N,64]
    int E)
{
    // Only LDS: H2 bounce, wave-private [16 edges][64 hid] bf16 (2KB/wave).
    __shared__ __align__(16) unsigned short H2[4 * 16 * 64];

    const int tid  = threadIdx.x;
    const int lane = tid & 63;
    const int wv   = tid >> 6;
    const int g    = lane >> 4;
    const int el   = lane & 15;

    unsigned short* const h2w = H2 + wv * (16 * 64);

    // persistent weight fragments: A row = lane&15, k = 8*(lane>>4)+j;
    // B col = lane&15, same k (identical mappings)
    bf16x8 wa[4][2], wb[4][2];
    f32x4  bias1[4];
    float  bias2s[4];
#pragma unroll
    for (int mt = 0; mt < 4; ++mt) {
        const int o = mt * 16 + el;
#pragma unroll
        for (int ks = 0; ks < 2; ++ks) {
            bf16x8 ta, tb;
#pragma unroll
            for (int j = 0; j < 8; ++j) {
                const int k = ks * 32 + 8 * g + j;
                ta[j] = (short)f2bf(W1a[k * 64 + o]);
                tb[j] = (short)f2bf(W1b[k * 64 + o]);
            }
            wa[mt][ks] = ta;
            wb[mt][ks] = tb;
        }
#pragma unroll
        for (int r = 0; r < 4; ++r) bias1[mt][r] = b1a[mt * 16 + 4 * g + r];
        bias2s[mt] = b1b[o];
    }

    const int ntile = (E + 15) >> 4;
    const int wid   = blockIdx.x * 4 + wv;
    const int nw    = gridDim.x * 4;

    const int sw = el & 7;   // H2 swizzle

    for (int t = wid; t < ntile; t += nw) {
        const int ebase = t << 4;

        // ---- meta: lane (g,el) gets sorted2 of edge el (broadcast read) ----
        int2 s2; int row;
        if (ebase + el < E) {
            s2 = sorted2[ebase + el];
            row = (int)((unsigned)s2.y >> 16);
        } else { s2 = int2{0, 0}; row = -1; }

        // ---- gather DIRECTLY into B-fragments: 2x32B per lane ----
        bf16x8 bf0, bf1;
        {
            const float4* xp = (const float4*)(x + (size_t)(s2.y & 0xFFFF) * 32 + 8 * g);
            const float4* ap = (const float4*)(eattr + (size_t)s2.x * 32 + 8 * g);
            const float4 x0 = xp[0], x1 = xp[1];
            const float4 a0v = ap[0], a1v = ap[1];
            bf0[0] = (short)f2bf(x0.x); bf0[1] = (short)f2bf(x0.y);
            bf0[2] = (short)f2bf(x0.z); bf0[3] = (short)f2bf(x0.w);
            bf0[4] = (short)f2bf(x1.x); bf0[5] = (short)f2bf(x1.y);
            bf0[6] = (short)f2bf(x1.z); bf0[7] = (short)f2bf(x1.w);
            bf1[0] = (short)f2bf(a0v.x); bf1[1] = (short)f2bf(a0v.y);
            bf1[2] = (short)f2bf(a0v.z); bf1[3] = (short)f2bf(a0v.w);
            bf1[4] = (short)f2bf(a1v.x); bf1[5] = (short)f2bf(a1v.y);
            bf1[6] = (short)f2bf(a1v.z); bf1[7] = (short)f2bf(a1v.w);
        }

        // ---- layer 1: D1 = W1a^T (A) x In^T (B) -> neuron-major ----
        f32x4 a0 = bias1[0], a1 = bias1[1], a2 = bias1[2], a3 = bias1[3];
        a0 = __builtin_amdgcn_mfma_f32_16x16x32_bf16(wa[0][0], bf0, a0, 0, 0, 0);
        a1 = __builtin_amdgcn_mfma_f32_16x16x32_bf16(wa[1][0], bf0, a1, 0, 0, 0);
        a2 = __builtin_amdgcn_mfma_f32_16x16x32_bf16(wa[2][0], bf0, a2, 0, 0, 0);
        a3 = __builtin_amdgcn_mfma_f32_16x16x32_bf16(wa[3][0], bf0, a3, 0, 0, 0);
        a0 = __builtin_amdgcn_mfma_f32_16x16x32_bf16(wa[0][1], bf1, a0, 0, 0, 0);
        a1 = __builtin_amdgcn_mfma_f32_16x16x32_bf16(wa[1][1], bf1, a1, 0, 0, 0);
        a2 = __builtin_amdgcn_mfma_f32_16x16x32_bf16(wa[2][1], bf1, a2, 0, 0, 0);
        a3 = __builtin_amdgcn_mfma_f32_16x16x32_bf16(wa[3][1], bf1, a3, 0, 0, 0);

        // ---- relu -> bf16 -> H2 (wave-private, swizzled) ----
        unsigned short* hrow = h2w + el * 64;
        {
            f32x4 accs[4] = {a0, a1, a2, a3};
#pragma unroll
            for (int mt = 0; mt < 4; ++mt) {
                unsigned short pk[4];
#pragma unroll
                for (int r = 0; r < 4; ++r) pk[r] = f2bf(fmaxf(accs[mt][r], 0.f));
                const int hid   = mt * 16 + 4 * g;
                const int chunk = hid >> 3;
                const int off   = hid & 7;
                *(uint2*)(hrow + ((chunk ^ sw) * 8 + off)) = *(uint2*)pk;
            }
        }

        // ---- layer 2, operand-swapped: D2 = H1 (A) x W1b (B) -> EDGE-major ----
        const bf16x8 hb0 = *(const bf16x8*)(hrow + (((0 + g) ^ sw) * 8));
        const bf16x8 hb1 = *(const bf16x8*)(hrow + (((4 + g) ^ sw) * 8));
        f32x4 d0 = {bias2s[0], bias2s[0], bias2s[0], bias2s[0]};
        f32x4 d1 = {bias2s[1], bias2s[1], bias2s[1], bias2s[1]};
        f32x4 d2 = {bias2s[2], bias2s[2], bias2s[2], bias2s[2]};
        f32x4 d3 = {bias2s[3], bias2s[3], bias2s[3], bias2s[3]};
        d0 = __builtin_amdgcn_mfma_f32_16x16x32_bf16(hb0, wb[0][0], d0, 0, 0, 0);
        d1 = __builtin_amdgcn_mfma_f32_16x16x32_bf16(hb0, wb[1][0], d1, 0, 0, 0);
        d2 = __builtin_amdgcn_mfma_f32_16x16x32_bf16(hb0, wb[2][0], d2, 0, 0, 0);
        d3 = __builtin_amdgcn_mfma_f32_16x16x32_bf16(hb0, wb[3][0], d3, 0, 0, 0);
        d0 = __builtin_amdgcn_mfma_f32_16x16x32_bf16(hb1, wb[0][1], d0, 0, 0, 0);
        d1 = __builtin_amdgcn_mfma_f32_16x16x32_bf16(hb1, wb[1][1], d1, 0, 0, 0);
        d2 = __builtin_amdgcn_mfma_f32_16x16x32_bf16(hb1, wb[2][1], d2, 0, 0, 0);
        d3 = __builtin_amdgcn_mfma_f32_16x16x32_bf16(hb1, wb[3][1], d3, 0, 0, 0);

        // ---- relu in registers ----
#pragma unroll
        for (int r = 0; r < 4; ++r) {
            d0[r] = fmaxf(d0[r], 0.f);
            d1[r] = fmaxf(d1[r], 0.f);
            d2[r] = fmaxf(d2[r], 0.f);
            d3[r] = fmaxf(d3[r], 0.f);
        }

        // ---- register-space segmented flush ----
        const int prevrow = __shfl(row, lane - 1);   // used for g==0 && el>0
        unsigned long long bmask =
            __ballot((g == 0) && (el > 0) && (row != prevrow));
        bmask = (bmask & 0xFFFEull) | 0x10000ull;    // bits 1..15 + sentinel@16

        int s = 0;
        while (s < 16) {
            const int e = s + 1 + (__ffsll(bmask >> (s + 1)) - 1);
            const int rowid = __shfl(row, s);
            if (rowid >= 0) {
                float s0 = 0.f, s1 = 0.f, s2v = 0.f, s3 = 0.f;
#pragma unroll
                for (int r = 0; r < 4; ++r) {
                    const int ej = 4 * g + r;
                    const bool in = (ej >= s) && (ej < e);
                    s0  += in ? d0[r] : 0.f;
                    s1  += in ? d1[r] : 0.f;
                    s2v += in ? d2[r] : 0.f;
                    s3  += in ? d3[r] : 0.f;
                }
                s0  += __shfl_xor(s0, 16);  s0  += __shfl_xor(s0, 32);
                s1  += __shfl_xor(s1, 16);  s1  += __shfl_xor(s1, 32);
                s2v += __shfl_xor(s2v, 16); s2v += __shfl_xor(s2v, 32);
                s3  += __shfl_xor(s3, 16);  s3  += __shfl_xor(s3, 32);
                const float val = (g == 0) ? s0 : (g == 1) ? s1
                                : (g == 2) ? s2v : s3;
                unsafeAtomicAdd(&summed[(size_t)rowid * 64 + lane], val);
            }
            s = e;
        }
    }
}

// ---------------- node MLP via MFMA ----------------

__global__ __launch_bounds__(256, 2) void node_mlp_mfma(
    const float* __restrict__ x,        // [N,32]
    const float* __restrict__ summed,   // [N,64]
    const int*   __restrict__ rowstart, // [N+1]
    const float* __restrict__ u,        // [G,16]
    const int*   __restrict__ batch,    // [N]
    const float* __restrict__ W2a,      // [112,64]
    const float* __restrict__ b2a,      // [64]
    const float* __restrict__ W2b,      // [64,32]
    const float* __restrict__ b2b,      // [32]
    float* __restrict__ out,            // [N,32]
    int N)
{
    __shared__ __align__(16) unsigned short In[64 * 128];  // 16KB
    __shared__ __align__(16) unsigned short H[64 * 64];    // 8KB

    const int tid  = threadIdx.x;
    const int lane = tid & 63;
    const int wv   = tid >> 6;
    const int g    = lane >> 4;
    const int el   = lane & 15;

    bf16x8 wa[4][4];
    f32x4  bias1[4];
#pragma unroll
    for (int mt = 0; mt < 4; ++mt) {
        const int o = mt * 16 + el;
#pragma unroll
        for (int ks = 0; ks < 4; ++ks) {
            bf16x8 ta;
#pragma unroll
            for (int j = 0; j < 8; ++j) {
                const int k = ks * 32 + 8 * g + j;
                ta[j] = (k < 112) ? (short)f2bf(W2a[k * 64 + o]) : (short)0;
            }
            wa[mt][ks] = ta;
        }
#pragma unroll
        for (int r = 0; r < 4; ++r) bias1[mt][r] = b2a[mt * 16 + 4 * g + r];
    }
    bf16x8 wb[2][2];
    float  bias2s[2];
#pragma unroll
    for (int nt = 0; nt < 2; ++nt) {
        const int o = nt * 16 + el;
#pragma unroll
        for (int ks = 0; ks < 2; ++ks) {
            bf16x8 tb;
#pragma unroll
            for (int j = 0; j < 8; ++j) {
                const int k = ks * 32 + 8 * g + j;
                tb[j] = (short)f2bf(W2b[k * 32 + o]);
            }
            wb[nt][ks] = tb;
        }
        bias2s[nt] = b2b[o];
    }

    unsigned short* const inrow = In + (wv * 16) * 128;
    unsigned short* const hrow0 = H + (wv * 16) * 64;

    const int ntile = (N + 15) >> 4;
    const int wid   = blockIdx.x * 4 + wv;
    const int nw    = gridDim.x * 4;

    for (int t = wid; t < ntile; t += nw) {
        const int nbase = t << 4;

        // ---- stage 16 nodes: 4 lanes/node, 32-float segment each ----
        // row layout (128 bf16): [x(32) | agg(32) | agg(32) | u(16)+0(16)]
        {
            const int le = lane >> 2;
            const int p  = lane & 3;
            const int n  = nbase + le;
            float4 v[8];
            if (n < N) {
                if (p == 0) {
                    const float4* xp = (const float4*)(x + (size_t)n * 32);
#pragma unroll
                    for (int q = 0; q < 8; ++q) v[q] = xp[q];
                } else if (p < 3) {
                    const int cnt = rowstart[n + 1] - rowstart[n];
                    const float inv = 1.0f / fmaxf((float)cnt, 1.0f);
                    const float4* sp = (const float4*)(summed + (size_t)n * 64 + (p - 1) * 32);
#pragma unroll
                    for (int q = 0; q < 8; ++q) {
                        v[q] = sp[q];
                        v[q].x *= inv; v[q].y *= inv; v[q].z *= inv; v[q].w *= inv;
                    }
                } else {
                    const int gb = batch[n];
                    const float4* up = (const float4*)(u + (size_t)gb * 16);
#pragma unroll
                    for (int q = 0; q < 4; ++q) v[q] = up[q];
#pragma unroll
                    for (int q = 4; q < 8; ++q) v[q] = float4{0.f, 0.f, 0.f, 0.f};
                }
            } else {
#pragma unroll
                for (int q = 0; q < 8; ++q) v[q] = float4{0.f, 0.f, 0.f, 0.f};
            }
            const int sw = le & 7;
            unsigned short* row = inrow + le * 128;
#pragma unroll
            for (int q = 0; q < 4; ++q) {
                bf16x8 c;
                const float4 va = v[2 * q], vb = v[2 * q + 1];
                c[0] = (short)f2bf(va.x); c[1] = (short)f2bf(va.y);
                c[2] = (short)f2bf(va.z); c[3] = (short)f2bf(va.w);
                c[4] = (short)f2bf(vb.x); c[5] = (short)f2bf(vb.y);
                c[6] = (short)f2bf(vb.z); c[7] = (short)f2bf(vb.w);
                const int cc = 4 * p + q;
                const int ci = (cc & 8) | ((cc & 7) ^ sw);
                *(bf16x8*)(row + ci * 8) = c;
            }
        }

        // ---- layer 1: 16 MFMAs over K=128 ----
        const unsigned short* brow = inrow + el * 128;
        const int sw7 = el & 7;
        f32x4 a0 = bias1[0], a1 = bias1[1], a2 = bias1[2], a3 = bias1[3];
#pragma unroll
        for (int ks = 0; ks < 4; ++ks) {
            const int cc = ks * 4 + g;
            const int ci = (cc & 8) | ((cc & 7) ^ sw7);
            const bf16x8 bf = *(const bf16x8*)(brow + ci * 8);
            a0 = __builtin_amdgcn_mfma_f32_16x16x32_bf16(wa[0][ks], bf, a0, 0, 0, 0);
            a1 = __builtin_amdgcn_mfma_f32_16x16x32_bf16(wa[1][ks], bf, a1, 0, 0, 0);
            a2 = __builtin_amdgcn_mfma_f32_16x16x32_bf16(wa[2][ks], bf, a2, 0, 0, 0);
            a3 = __builtin_amdgcn_mfma_f32_16x16x32_bf16(wa[3][ks], bf, a3, 0, 0, 0);
        }

        // ---- relu -> bf16 -> H (swizzled by el&7) ----
        unsigned short* hrow = hrow0 + el * 64;
        {
            f32x4 accs[4] = {a0, a1, a2, a3};
#pragma unroll
            for (int mt = 0; mt < 4; ++mt) {
                unsigned short pk[4];
#pragma unroll
                for (int r = 0; r < 4; ++r) pk[r] = f2bf(fmaxf(accs[mt][r], 0.f));
                const int hid   = mt * 16 + 4 * g;
                const int chunk = hid >> 3;
                const int off   = hid & 7;
                *(uint2*)(hrow + ((chunk ^ sw7) * 8 + off)) = *(uint2*)pk;
            }
        }

        // ---- layer 2 operand-swapped: D = H (A) x W2b (B) -> node-major ----
        const bf16x8 hb0 = *(const bf16x8*)(hrow + (((0 + g) ^ sw7) * 8));
        const bf16x8 hb1 = *(const bf16x8*)(hrow + (((4 + g) ^ sw7) * 8));
        f32x4 dn0 = {bias2s[0], bias2s[0], bias2s[0], bias2s[0]};
        f32x4 dn1 = {bias2s[1], bias2s[1], bias2s[1], bias2s[1]};
        dn0 = __builtin_amdgcn_mfma_f32_16x16x32_bf16(hb0, wb[0][0], dn0, 0, 0, 0);
        dn1 = __builtin_amdgcn_mfma_f32_16x16x32_bf16(hb0, wb[1][0], dn1, 0, 0, 0);
        dn0 = __builtin_amdgcn_mfma_f32_16x16x32_bf16(hb1, wb[0][1], dn0, 0, 0, 0);
        dn1 = __builtin_amdgcn_mfma_f32_16x16x32_bf16(hb1, wb[1][1], dn1, 0, 0, 0);

        // ---- store: lane holds node 4g+r, out nt*16+el ----
        if (nbase + 16 <= N) {
#pragma unroll
            for (int r = 0; r < 4; ++r) {
                float* dst = out + (size_t)(nbase + 4 * g + r) * 32 + el;
                dst[0]  = dn0[r];
                dst[16] = dn1[r];
            }
        } else {
#pragma unroll
            for (int r = 0; r < 4; ++r) {
                const int n = nbase + 4 * g + r;
                if (n < N) {
                    float* dst = out + (size_t)n * 32 + el;
                    dst[0]  = dn0[r];
                    dst[16] = dn1[r];
                }
            }
        }
    }
}

extern "C" void kernel_launch(void* const* d_in, const int* in_sizes, int n_in,
                              void* d_out, int out_size, void* d_ws, size_t ws_size,
                              hipStream_t stream) {
    const float* x     = (const float*)d_in[0];
    const int*   eidx  = (const int*)d_in[1];   // [2,E] int32
    const float* eattr = (const float*)d_in[2];
    const float* u     = (const float*)d_in[3];
    const int*   batch = (const int*)d_in[4];
    const float* W1a   = (const float*)d_in[5];
    const float* b1a   = (const float*)d_in[6];
    const float* W1b   = (const float*)d_in[7];
    const float* b1b   = (const float*)d_in[8];
    const float* W2a   = (const float*)d_in[9];
    const float* b2a   = (const float*)d_in[10];
    const float* W2b   = (const float*)d_in[11];
    const float* b2b   = (const float*)d_in[12];
    float* out = (float*)d_out;

    const int N = in_sizes[0] / 32;
    const int E = in_sizes[1] / 2;
    const int* erow = eidx;
    const int* ecol = eidx + E;

    // ws: sorted2[E] | summed[N*64] f32 | counts[N] | rowstart[N+1] | cursor[N] | bsum[256]
    int2*  sorted2  = (int2*)d_ws;
    float* summed   = (float*)(sorted2 + E);
    int*   counts   = (int*)(summed + (size_t)N * 64);
    int*   rowstart = counts + N;
    int*   cursor   = rowstart + (N + 1);
    int*   bsum     = cursor + N;

    // zero summed + counts (contiguous)
    hipMemsetAsync(summed, 0, ((size_t)N * 64 + N) * sizeof(float), stream);

    count_rows<<<1024, 256, 0, stream>>>(erow, counts, E);
    const int nb = (N + 255) / 256;
    scan_blocks<<<nb, 256, 0, stream>>>(counts, rowstart, bsum, N);
    scan_bsum<<<1, 256, 0, stream>>>(bsum, nb);
    scan_add<<<nb, 256, 0, stream>>>(rowstart, cursor, bsum, N, E);
    permute_edges<<<1024, 256, 0, stream>>>(erow, ecol, cursor, sorted2, E);

    edge_mlp_mfma<<<4096, 256, 0, stream>>>(x, sorted2, eattr,
                                            W1a, b1a, W1b, b1b, summed, E);
    node_mlp_mfma<<<784, 256, 0, stream>>>(x, summed, rowstart, u, batch,
                                           W2a, b2a, W2b, b2b, out, N);
}